// Round 8
// baseline (466.932 us; speedup 1.0000x reference)
//
#include <hip/hip_runtime.h>

// GAT as flash-attention, round 8 = R7 + raw-barrier (no vmcnt drain):
//  - __syncthreads() forces s_waitcnt vmcnt(0) before s_barrier, draining the
//    adj HBM stream every tile (~900 cyc exposed). The barrier only needs to
//    order LDS ops -> use s_waitcnt lgkmcnt(0) + raw s_barrier; adj loads ride
//    across barriers in the vmcnt queue.
//  - adj prefetched 2 tiles ahead (wave-private VGPRs, never drained).
//  - everything else identical to R7: double-buffered XOR-swizzled LDS,
//    fixed-scale softmax, S^T MFMA formulation, 4-way j-split, 1024 blocks.

typedef __attribute__((ext_vector_type(4))) float f32x4;
typedef __attribute__((ext_vector_type(4))) _Float16 h16x4;
typedef __attribute__((ext_vector_type(8))) _Float16 h16x8;
typedef __attribute__((ext_vector_type(2))) __fp16 fp16x2;

#define L2E 1.4426950408889634f

// Barrier that orders LDS only: per-wave lgkm drain + raw s_barrier.
// Does NOT drain vmcnt (wave-private global loads stay in flight).
__device__ __forceinline__ void lds_barrier() {
  asm volatile("s_waitcnt lgkmcnt(0)" ::: "memory");
  __builtin_amdgcn_s_barrier();
}

// ---------------- phase 1: h = x@W (fp32), scaled biases, fp16 packs --------
__global__ __launch_bounds__(256) void gat_phase1(
    const float* __restrict__ x,        // [4][4096][128]
    const float* __restrict__ W,        // [128][64]
    const float* __restrict__ a,        // [192]
    _Float16* __restrict__ h16,         // [4][4096][64]
    _Float16* __restrict__ hT16,        // [4][64][4096]
    _Float16* __restrict__ q16,         // [4][4096][64]  (pre-scaled by log2e)
    float* __restrict__ sS,             // [4][4096]      (pre-scaled by log2e)
    float* __restrict__ sN)             // [4][4096]      (pre-scaled by log2e)
{
  __shared__ float xs[32 * 132];        // x tile [row][k], stride 132
  __shared__ float ws[128 * 64];        // W natural [k][f] (broadcast/2-way)
  const int tid = threadIdx.x;
  const int bx  = blockIdx.x;
  const int b   = bx >> 7;
  const int n0  = (bx & 127) << 5;
  const float* xb = x + ((size_t)b * 4096 + n0) * 128;

#pragma unroll
  for (int p = 0; p < 4; ++p) {
    int idx = tid + p * 256;
    int row = idx >> 5, c4 = idx & 31;
    float4 v = ((const float4*)(xb + row * 128))[c4];
    *(float4*)&xs[row * 132 + c4 * 4] = v;
  }
#pragma unroll
  for (int p = 0; p < 8; ++p) {
    int idx = tid + p * 256;
    ((float4*)ws)[idx] = ((const float4*)W)[idx];
  }
  __syncthreads();

  const int tx = tid & 15;   // f = 4*tx + fi
  const int ty = tid >> 4;   // n = n0 + 2*ty + ri
  f32x4 acc0 = (f32x4){0.f, 0.f, 0.f, 0.f};
  f32x4 acc1 = (f32x4){0.f, 0.f, 0.f, 0.f};

#pragma unroll 8
  for (int k = 0; k < 128; k += 4) {
    f32x4 x0 = *(const f32x4*)&xs[(2 * ty) * 132 + k];
    f32x4 x1 = *(const f32x4*)&xs[(2 * ty + 1) * 132 + k];
    f32x4 w0 = *(const f32x4*)&ws[(k + 0) * 64 + 4 * tx];
    f32x4 w1 = *(const f32x4*)&ws[(k + 1) * 64 + 4 * tx];
    f32x4 w2 = *(const f32x4*)&ws[(k + 2) * 64 + 4 * tx];
    f32x4 w3 = *(const f32x4*)&ws[(k + 3) * 64 + 4 * tx];
    acc0 += x0.x * w0 + x0.y * w1 + x0.z * w2 + x0.w * w3;
    acc1 += x1.x * w0 + x1.y * w1 + x1.z * w2 + x1.w * w3;
  }
  float acc[2][4] = {{acc0.x, acc0.y, acc0.z, acc0.w},
                     {acc1.x, acc1.y, acc1.z, acc1.w}};

  float a1r[4], a2r[4], a3r[4];
#pragma unroll
  for (int f = 0; f < 4; ++f) {
    a1r[f] = a[4 * tx + f] * L2E;
    a2r[f] = a[64 + 4 * tx + f] * L2E;
    a3r[f] = a[128 + 4 * tx + f] * L2E;
  }
  const size_t bN = (size_t)b * 4096;
#pragma unroll
  for (int r = 0; r < 2; ++r) {
    float p1 = 0.f, p2 = 0.f;
#pragma unroll
    for (int f = 0; f < 4; ++f) { p1 += acc[r][f] * a1r[f]; p2 += acc[r][f] * a2r[f]; }
#pragma unroll
    for (int m = 1; m < 16; m <<= 1) {
      p1 += __shfl_xor(p1, m, 64);
      p2 += __shfl_xor(p2, m, 64);
    }
    if (tx == 0) {
      int n = n0 + 2 * ty + r;
      sS[bN + n] = p1;
      sN[bN + n] = p2;
    }
  }
#pragma unroll
  for (int r = 0; r < 2; ++r) {
    int n = n0 + 2 * ty + r;
    h16x4 hv, qv;
#pragma unroll
    for (int f = 0; f < 4; ++f) {
      hv[f] = (_Float16)acc[r][f];
      qv[f] = (_Float16)(acc[r][f] * a3r[f]);
    }
    *(h16x4*)&h16[(bN + n) * 64 + 4 * tx] = hv;
    *(h16x4*)&q16[(bN + n) * 64 + 4 * tx] = qv;
  }
  __syncthreads();                       // xs reads done; reuse as hT staging
  _Float16* hTs = (_Float16*)xs;         // [64][40] halves
#pragma unroll
  for (int f = 0; f < 4; ++f)
#pragma unroll
    for (int r = 0; r < 2; ++r)
      hTs[(4 * tx + f) * 40 + 2 * ty + r] = (_Float16)acc[r][f];
  __syncthreads();
  {
    int f = tid >> 2, part = tid & 3;
    uint4 v = *(uint4*)&hTs[f * 40 + 8 * part];
    *(uint4*)&hT16[((size_t)b * 64 + f) * 4096 + n0 + 8 * part] = v;
  }
}

// ---------------- phase 2: masked softmax-attention partials ----------------
// 1024 blocks (b(4), split(4), itile(64)) x 256 thr (4 waves x 16 rows).
// j-quarter = 1024 = 16 tiles of 64. Double-buffered XOR-swizzled LDS,
// one lds_barrier/tile (no vmcnt drain). adj prefetched 2 tiles ahead.
// MFMA layouts: 16x16x32 A[m=lane&15][k=qd*8+j], B[k=qd*8+j][n=lane&15],
//               16x16x16 A[m=lane&15][k=qd*4+r], B[k=qd*4+r][n=lane&15],
//               C/D row=4*qd+reg, col=lane&15.
__global__ __launch_bounds__(256, 4) void gat_phase2(
    const _Float16* __restrict__ h16,
    const _Float16* __restrict__ hT16,
    const _Float16* __restrict__ q16,
    const float* __restrict__ sS,
    const float* __restrict__ sN,
    const int* __restrict__ adj,
    float* __restrict__ Opart,          // [4][16384][64]
    float* __restrict__ lpart)          // [4][16384]
{
  __shared__ _Float16 Kb[2][4096];   // K tile [j][f], stride 64, chunk^(j&7)
  __shared__ _Float16 Tb[2][4096];   // V^T tile [f][j], stride 64, 8B-chunk^f
  __shared__ float sNl[1024];

  const int tid = threadIdx.x;
  const int w = tid >> 6, lane = tid & 63;
  const int qd = lane >> 4, c = lane & 15;
  const int bx = blockIdx.x;
  const int b = bx & 3;
  const int split = (bx >> 2) & 3;
  const int it = bx >> 4;
  const int i0 = it * 64 + w * 16;
  const int jq0 = split * 1024;
  const size_t bN = (size_t)b * 4096;

  // Q fragment (B-op of S^T): lane holds Q[i=i0+c][f-slice]
  const _Float16* qrow = q16 + (bN + i0 + c) * 64;
  h16x8 Qf0 = *(const h16x8*)(qrow + qd * 8);
  h16x8 Qf1 = *(const h16x8*)(qrow + 32 + qd * 8);
  const float ss = sS[bN + i0 + c];

  const int* abase = adj + (bN + i0 + c) * 4096 + jq0 + 4 * qd;

  // staging addressing: thread -> rows srow, srow+32; 16B chunk (swizzled)
  const int srow = tid >> 3, chunk = tid & 7;
  const int ksw = (chunk ^ (srow & 7)) << 3;
  const int tsw = (chunk ^ ((srow >> 1) & 7)) << 3;
  const bool tswap = (srow & 1);
  const _Float16* hsrc = h16 + (bN + jq0 + srow) * 64 + chunk * 8;
  const _Float16* tsrc = hT16 + ((size_t)b * 64 + srow) * 4096 + jq0 + chunk * 8;

  f32x4 O[4];
#pragma unroll
  for (int ft = 0; ft < 4; ++ft) O[ft] = (f32x4){0.f, 0.f, 0.f, 0.f};
  float lsum = 0.f;

  // stage tile 0 into buffer 0, sN into LDS, adj tiles 0 & 1 into regs
  {
    uint4 k0 = *(const uint4*)hsrc, k1 = *(const uint4*)(hsrc + 32 * 64);
    uint4 t0 = *(const uint4*)tsrc, t1 = *(const uint4*)(tsrc + 32 * 4096);
    *(uint4*)&Kb[0][srow * 64 + ksw] = k0;
    *(uint4*)&Kb[0][(srow + 32) * 64 + ksw] = k1;
    uint4 s0 = tswap ? (uint4){t0.z, t0.w, t0.x, t0.y} : t0;
    uint4 s1 = tswap ? (uint4){t1.z, t1.w, t1.x, t1.y} : t1;
    *(uint4*)&Tb[0][srow * 64 + tsw] = s0;
    *(uint4*)&Tb[0][(srow + 32) * 64 + tsw] = s1;
  }
  ((f32x4*)sNl)[tid] = *(const f32x4*)(sN + bN + jq0 + 4 * tid);
  uint4 av[4], av1[4];
#pragma unroll
  for (int ct = 0; ct < 4; ++ct) av[ct] = *(const uint4*)(abase + 16 * ct);
#pragma unroll
  for (int ct = 0; ct < 4; ++ct) av1[ct] = *(const uint4*)(abase + 64 + 16 * ct);

#pragma unroll 2
  for (int t = 0; t < 16; ++t) {
    lds_barrier();                                  // buf[t&1] (+sNl) visible

    uint4 kr0, kr1, tr0, tr1;
    uint4 av2[4] = {av1[0], av1[1], av1[2], av1[3]};
    if (t < 15) {
      // K/V staging loads FIRST (L2-hot): ds_write waits vmcnt(4), leaving
      // the adj loads below outstanding across the next barrier
      const _Float16* hs = hsrc + (t + 1) * 4096;
      const _Float16* ts = tsrc + (t + 1) * 64;
      kr0 = *(const uint4*)hs; kr1 = *(const uint4*)(hs + 32 * 64);
      tr0 = *(const uint4*)ts; tr1 = *(const uint4*)(ts + 32 * 4096);
    }
    if (t < 14) {                                   // adj 2 tiles ahead (HBM)
#pragma unroll
      for (int ct = 0; ct < 4; ++ct)
        av2[ct] = *(const uint4*)(abase + (t + 2) * 64 + 16 * ct);
    }

    const _Float16* Kc = &Kb[t & 1][0];
    const _Float16* Tc = &Tb[t & 1][0];
#pragma unroll
    for (int ct = 0; ct < 4; ++ct) {
      const int krow = 16 * ct + c;
      h16x8 Kf0 = *(const h16x8*)&Kc[krow * 64 + ((qd ^ (c & 7)) << 3)];
      h16x8 Kf1 = *(const h16x8*)&Kc[krow * 64 + (((qd + 4) ^ (c & 7)) << 3)];
      f32x4 Sv = (f32x4){0.f, 0.f, 0.f, 0.f};
      Sv = __builtin_amdgcn_mfma_f32_16x16x32_f16(Kf0, Qf0, Sv, 0, 0, 0);
      Sv = __builtin_amdgcn_mfma_f32_16x16x32_f16(Kf1, Qf1, Sv, 0, 0, 0);

      f32x4 snv = ((const f32x4*)sNl)[t * 16 + 4 * ct + qd];   // broadcast
      f32x4 ev = Sv + snv + ss;                     // e * log2e
      f32x4 tv = __builtin_elementwise_max(ev, ev * 0.2f);  // leakyrelu
      float p0 = __builtin_amdgcn_exp2f(tv.x);
      float p1 = __builtin_amdgcn_exp2f(tv.y);
      float p2 = __builtin_amdgcn_exp2f(tv.z);
      float p3 = __builtin_amdgcn_exp2f(tv.w);
      p0 = av[ct].x ? p0 : 0.f;
      p1 = av[ct].y ? p1 : 0.f;
      p2 = av[ct].z ? p2 : 0.f;
      p3 = av[ct].w ? p3 : 0.f;
      lsum += (p0 + p1) + (p2 + p3);
      fp16x2 plo = __builtin_amdgcn_cvt_pkrtz(p0, p1);
      fp16x2 phi = __builtin_amdgcn_cvt_pkrtz(p2, p3);
      h16x4 Pf = (h16x4){(_Float16)plo.x, (_Float16)plo.y,
                         (_Float16)phi.x, (_Float16)phi.y};  // P^T[j][i=c]

      // O^T[f][i] += V^T[f][j] * P^T[j][i]
#pragma unroll
      for (int ft = 0; ft < 4; ++ft) {
        h16x4 Vf = *(const h16x4*)&Tc[(16 * ft + c) * 64 +
                                      (((4 * ct + qd) ^ c) << 2)];
        O[ft] = __builtin_amdgcn_mfma_f32_16x16x16f16(Vf, Pf, O[ft], 0, 0, 0);
      }
    }

    if (t < 15) {                                   // fill the other buffer
      _Float16* K2 = &Kb[(t & 1) ^ 1][0];
      _Float16* T2 = &Tb[(t & 1) ^ 1][0];
      *(uint4*)&K2[srow * 64 + ksw] = kr0;
      *(uint4*)&K2[(srow + 32) * 64 + ksw] = kr1;
      uint4 s0 = tswap ? (uint4){tr0.z, tr0.w, tr0.x, tr0.y} : tr0;
      uint4 s1 = tswap ? (uint4){tr1.z, tr1.w, tr1.x, tr1.y} : tr1;
      *(uint4*)&T2[srow * 64 + tsw] = s0;
      *(uint4*)&T2[(srow + 32) * 64 + tsw] = s1;
    }
#pragma unroll
    for (int ct = 0; ct < 4; ++ct) { av[ct] = av1[ct]; av1[ct] = av2[ct]; }
  }

  // l: sum over qd groups (full j-quarter per row i=i0+c)
  lsum += __shfl_xor(lsum, 16, 64);
  lsum += __shfl_xor(lsum, 32, 64);

  float* orow = Opart + ((size_t)split * 16384 + bN + i0 + c) * 64;
#pragma unroll
  for (int ft = 0; ft < 4; ++ft)
    *(f32x4*)(orow + 16 * ft + 4 * qd) = O[ft];
  if (lane < 16) lpart[split * 16384 + bN + i0 + c] = lsum;
}

// ---------------- phase 3: combine splits + normalize + ELU ----------------
__global__ __launch_bounds__(256) void gat_combine(
    const float* __restrict__ Opart, const float* __restrict__ lpart,
    float* __restrict__ out)
{
  const int tid = threadIdx.x;
  const size_t row = (size_t)blockIdx.x * 16 + (tid >> 4);
  const int f4 = (tid & 15) * 4;
  const size_t R = 16384;
  float l = lpart[row] + lpart[R + row] + lpart[2 * R + row] + lpart[3 * R + row];
  f32x4 o = *(const f32x4*)&Opart[row * 64 + f4];
  o += *(const f32x4*)&Opart[(R + row) * 64 + f4];
  o += *(const f32x4*)&Opart[(2 * R + row) * 64 + f4];
  o += *(const f32x4*)&Opart[(3 * R + row) * 64 + f4];
  float inv = 1.0f / l;
  float4 res;
  float v;
  v = o.x * inv; res.x = v > 0.f ? v : __expf(v) - 1.f;
  v = o.y * inv; res.y = v > 0.f ? v : __expf(v) - 1.f;
  v = o.z * inv; res.z = v > 0.f ? v : __expf(v) - 1.f;
  v = o.w * inv; res.w = v > 0.f ? v : __expf(v) - 1.f;
  *(float4*)&out[row * 64 + f4] = res;
}

extern "C" void kernel_launch(void* const* d_in, const int* in_sizes, int n_in,
                              void* d_out, int out_size, void* d_ws, size_t ws_size,
                              hipStream_t stream) {
  const float* x  = (const float*)d_in[0];
  const int* adj  = (const int*)d_in[1];
  const float* W  = (const float*)d_in[2];
  const float* a  = (const float*)d_in[3];
  float* out = (float*)d_out;

  char* ws = (char*)d_ws;
  _Float16* h16  = (_Float16*)(ws);                      // 2 MB
  _Float16* hT16 = (_Float16*)(ws + (2u << 20));         // 2 MB
  _Float16* q16  = (_Float16*)(ws + (4u << 20));         // 2 MB
  float* sS = (float*)(ws + (6u << 20));                 // 64 KB
  float* sN = (float*)(ws + (6u << 20) + (64u << 10));   // 64 KB
  float* Opart = (float*)(ws + (6u << 20) + (128u << 10));               // 16.8 MB
  float* lpart = (float*)(ws + (6u << 20) + (128u << 10) + (17u << 20)); // 256 KB

  gat_phase1<<<512, 256, 0, stream>>>(x, W, a, h16, hT16, q16, sS, sN);
  gat_phase2<<<1024, 256, 0, stream>>>(h16, hT16, q16, sS, sN, adj, Opart, lpart);
  gat_combine<<<1024, 256, 0, stream>>>(Opart, lpart, out);
}

// Round 9
// 440.017 us; speedup vs baseline: 1.0612x; 1.0612x over previous
//
#include <hip/hip_runtime.h>

// GAT as flash-attention, round 9 = R5's decomposition + R7's phase2 fixes.
//  - adj CANNOT stream fast from phase2's access shape (R8 measured 1.9 TB/s:
//    64 B granules scattered over 16 KB-strided rows). gat_mask streams it
//    with one wave per row (256 B/inst contiguous, sequential) at ~6 TB/s
//    into a 64-bit-per-64j bitmask (8.4 MB, L2-hot for phase2).
//  - phase2: double-buffered XOR-swizzled LDS (0 conflicts), ONE
//    __syncthreads per 64-j tile, staging issued post-barrier, mask = 8 B/tile.
//    Only L2/L3-hot loads in the vmcnt queue -> barrier drain is cheap.
//  - fixed-scale softmax (exp2, no running max); S^T MFMA formulation;
//    4-way j-split, 1024 blocks, 16-row waves. No inline-asm barriers (R8).

typedef __attribute__((ext_vector_type(4))) float f32x4;
typedef __attribute__((ext_vector_type(4))) _Float16 h16x4;
typedef __attribute__((ext_vector_type(8))) _Float16 h16x8;
typedef __attribute__((ext_vector_type(2))) __fp16 fp16x2;

#define L2E 1.4426950408889634f

// ---------------- phase 0: adj -> bitmask (pure HBM stream) ----------------
// 4096 blocks x 256 thr; wave w owns row bx*4+w; 256 B/inst contiguous.
__global__ __launch_bounds__(256) void gat_mask(
    const int* __restrict__ adj,                 // [4][4096][4096]
    unsigned long long* __restrict__ mask)       // [4][4096][64]
{
  const int tid = threadIdx.x;
  const int w = tid >> 6, lane = tid & 63;
  const size_t row = (size_t)blockIdx.x * 4 + w;
  const int* ap = adj + row * 4096 + lane;
  unsigned long long* mp = mask + row * 64;
#pragma unroll 4
  for (int s = 0; s < 64; ++s) {
    int v = ap[s * 64];
    unsigned long long m = __ballot(v > 0);      // bit l = adj[row][s*64+l]>0
    if (lane == 0) mp[s] = m;
  }
}

// ---------------- phase 1: h = x@W (fp32), scaled biases, fp16 packs --------
__global__ __launch_bounds__(256) void gat_phase1(
    const float* __restrict__ x,        // [4][4096][128]
    const float* __restrict__ W,        // [128][64]
    const float* __restrict__ a,        // [192]
    _Float16* __restrict__ h16,         // [4][4096][64]
    _Float16* __restrict__ hT16,        // [4][64][4096]
    _Float16* __restrict__ q16,         // [4][4096][64]  (pre-scaled by log2e)
    float* __restrict__ sS,             // [4][4096]      (pre-scaled by log2e)
    float* __restrict__ sN)             // [4][4096]      (pre-scaled by log2e)
{
  __shared__ float xs[32 * 132];        // x tile [row][k], stride 132
  __shared__ float ws[128 * 64];        // W natural [k][f] (broadcast/2-way)
  const int tid = threadIdx.x;
  const int bx  = blockIdx.x;
  const int b   = bx >> 7;
  const int n0  = (bx & 127) << 5;
  const float* xb = x + ((size_t)b * 4096 + n0) * 128;

#pragma unroll
  for (int p = 0; p < 4; ++p) {
    int idx = tid + p * 256;
    int row = idx >> 5, c4 = idx & 31;
    float4 v = ((const float4*)(xb + row * 128))[c4];
    *(float4*)&xs[row * 132 + c4 * 4] = v;
  }
#pragma unroll
  for (int p = 0; p < 8; ++p) {
    int idx = tid + p * 256;
    ((float4*)ws)[idx] = ((const float4*)W)[idx];
  }
  __syncthreads();

  const int tx = tid & 15;   // f = 4*tx + fi
  const int ty = tid >> 4;   // n = n0 + 2*ty + ri
  f32x4 acc0 = (f32x4){0.f, 0.f, 0.f, 0.f};
  f32x4 acc1 = (f32x4){0.f, 0.f, 0.f, 0.f};

#pragma unroll 8
  for (int k = 0; k < 128; k += 4) {
    f32x4 x0 = *(const f32x4*)&xs[(2 * ty) * 132 + k];
    f32x4 x1 = *(const f32x4*)&xs[(2 * ty + 1) * 132 + k];
    f32x4 w0 = *(const f32x4*)&ws[(k + 0) * 64 + 4 * tx];
    f32x4 w1 = *(const f32x4*)&ws[(k + 1) * 64 + 4 * tx];
    f32x4 w2 = *(const f32x4*)&ws[(k + 2) * 64 + 4 * tx];
    f32x4 w3 = *(const f32x4*)&ws[(k + 3) * 64 + 4 * tx];
    acc0 += x0.x * w0 + x0.y * w1 + x0.z * w2 + x0.w * w3;
    acc1 += x1.x * w0 + x1.y * w1 + x1.z * w2 + x1.w * w3;
  }
  float acc[2][4] = {{acc0.x, acc0.y, acc0.z, acc0.w},
                     {acc1.x, acc1.y, acc1.z, acc1.w}};

  float a1r[4], a2r[4], a3r[4];
#pragma unroll
  for (int f = 0; f < 4; ++f) {
    a1r[f] = a[4 * tx + f] * L2E;
    a2r[f] = a[64 + 4 * tx + f] * L2E;
    a3r[f] = a[128 + 4 * tx + f] * L2E;
  }
  const size_t bN = (size_t)b * 4096;
#pragma unroll
  for (int r = 0; r < 2; ++r) {
    float p1 = 0.f, p2 = 0.f;
#pragma unroll
    for (int f = 0; f < 4; ++f) { p1 += acc[r][f] * a1r[f]; p2 += acc[r][f] * a2r[f]; }
#pragma unroll
    for (int m = 1; m < 16; m <<= 1) {
      p1 += __shfl_xor(p1, m, 64);
      p2 += __shfl_xor(p2, m, 64);
    }
    if (tx == 0) {
      int n = n0 + 2 * ty + r;
      sS[bN + n] = p1;
      sN[bN + n] = p2;
    }
  }
#pragma unroll
  for (int r = 0; r < 2; ++r) {
    int n = n0 + 2 * ty + r;
    h16x4 hv, qv;
#pragma unroll
    for (int f = 0; f < 4; ++f) {
      hv[f] = (_Float16)acc[r][f];
      qv[f] = (_Float16)(acc[r][f] * a3r[f]);
    }
    *(h16x4*)&h16[(bN + n) * 64 + 4 * tx] = hv;
    *(h16x4*)&q16[(bN + n) * 64 + 4 * tx] = qv;
  }
  __syncthreads();                       // xs reads done; reuse as hT staging
  _Float16* hTs = (_Float16*)xs;         // [64][40] halves
#pragma unroll
  for (int f = 0; f < 4; ++f)
#pragma unroll
    for (int r = 0; r < 2; ++r)
      hTs[(4 * tx + f) * 40 + 2 * ty + r] = (_Float16)acc[r][f];
  __syncthreads();
  {
    int f = tid >> 2, part = tid & 3;
    uint4 v = *(uint4*)&hTs[f * 40 + 8 * part];
    *(uint4*)&hT16[((size_t)b * 64 + f) * 4096 + n0 + 8 * part] = v;
  }
}

// ---------------- phase 2: masked softmax-attention partials ----------------
// 1024 blocks (b(4), split(4), itile(64)) x 256 thr (4 waves x 16 rows).
// j-quarter = 1024 = 16 tiles of 64. Double-buffered XOR-swizzled LDS,
// one __syncthreads/tile. All global reads L2/L3-hot; mask = 8 B/tile/lane.
// MFMA layouts: 16x16x32 A[m=lane&15][k=qd*8+j], B[k=qd*8+j][n=lane&15],
//               16x16x16 A[m=lane&15][k=qd*4+r], B[k=qd*4+r][n=lane&15],
//               C/D row=4*qd+reg, col=lane&15.
__global__ __launch_bounds__(256, 4) void gat_phase2(
    const _Float16* __restrict__ h16,
    const _Float16* __restrict__ hT16,
    const _Float16* __restrict__ q16,
    const float* __restrict__ sS,
    const float* __restrict__ sN,
    const unsigned long long* __restrict__ mask,  // [4][4096][64]
    float* __restrict__ Opart,          // [4][16384][64]
    float* __restrict__ lpart)          // [4][16384]
{
  __shared__ _Float16 Kb[2][4096];   // K tile [j][f], stride 64, chunk^(j&7)
  __shared__ _Float16 Tb[2][4096];   // V^T tile [f][j], stride 64, 8B-chunk^f
  __shared__ float sNl[1024];

  const int tid = threadIdx.x;
  const int w = tid >> 6, lane = tid & 63;
  const int qd = lane >> 4, c = lane & 15;
  const int bx = blockIdx.x;
  const int b = bx & 3;
  const int split = (bx >> 2) & 3;
  const int it = bx >> 4;
  const int i0 = it * 64 + w * 16;
  const int jq0 = split * 1024;
  const size_t bN = (size_t)b * 4096;

  // Q fragment (B-op of S^T): lane holds Q[i=i0+c][f-slice]
  const _Float16* qrow = q16 + (bN + i0 + c) * 64;
  h16x8 Qf0 = *(const h16x8*)(qrow + qd * 8);
  h16x8 Qf1 = *(const h16x8*)(qrow + 32 + qd * 8);
  const float ss = sS[bN + i0 + c];

  const unsigned long long* mrow = mask + (bN + i0 + c) * 64 + (jq0 >> 6);

  // staging addressing: thread -> rows srow, srow+32; 16B chunk (swizzled)
  const int srow = tid >> 3, chunk = tid & 7;
  const int ksw = (chunk ^ (srow & 7)) << 3;
  const int tsw = (chunk ^ ((srow >> 1) & 7)) << 3;
  const bool tswap = (srow & 1);
  const _Float16* hsrc = h16 + (bN + jq0 + srow) * 64 + chunk * 8;
  const _Float16* tsrc = hT16 + ((size_t)b * 64 + srow) * 4096 + jq0 + chunk * 8;

  f32x4 O[4];
#pragma unroll
  for (int ft = 0; ft < 4; ++ft) O[ft] = (f32x4){0.f, 0.f, 0.f, 0.f};
  float lsum = 0.f;

  // stage tile 0 into buffer 0, sN into LDS, mask tile 0 into reg
  {
    uint4 k0 = *(const uint4*)hsrc, k1 = *(const uint4*)(hsrc + 32 * 64);
    uint4 t0 = *(const uint4*)tsrc, t1 = *(const uint4*)(tsrc + 32 * 4096);
    *(uint4*)&Kb[0][srow * 64 + ksw] = k0;
    *(uint4*)&Kb[0][(srow + 32) * 64 + ksw] = k1;
    uint4 s0 = tswap ? (uint4){t0.z, t0.w, t0.x, t0.y} : t0;
    uint4 s1 = tswap ? (uint4){t1.z, t1.w, t1.x, t1.y} : t1;
    *(uint4*)&Tb[0][srow * 64 + tsw] = s0;
    *(uint4*)&Tb[0][(srow + 32) * 64 + tsw] = s1;
  }
  ((f32x4*)sNl)[tid] = *(const f32x4*)(sN + bN + jq0 + 4 * tid);
  unsigned long long m64 = mrow[0];

  for (int t = 0; t < 16; ++t) {
    __syncthreads();                                // buf[t&1] (+sNl) visible

    uint4 kr0, kr1, tr0, tr1;
    unsigned long long mn = m64;
    if (t < 15) {                                   // all L2/L3-hot loads
      const _Float16* hs = hsrc + (t + 1) * 4096;
      const _Float16* ts = tsrc + (t + 1) * 64;
      kr0 = *(const uint4*)hs; kr1 = *(const uint4*)(hs + 32 * 64);
      tr0 = *(const uint4*)ts; tr1 = *(const uint4*)(ts + 32 * 4096);
      mn = mrow[t + 1];
    }

    const _Float16* Kc = &Kb[t & 1][0];
    const _Float16* Tc = &Tb[t & 1][0];
#pragma unroll
    for (int ct = 0; ct < 4; ++ct) {
      const int krow = 16 * ct + c;
      h16x8 Kf0 = *(const h16x8*)&Kc[krow * 64 + ((qd ^ (c & 7)) << 3)];
      h16x8 Kf1 = *(const h16x8*)&Kc[krow * 64 + (((qd + 4) ^ (c & 7)) << 3)];
      f32x4 Sv = (f32x4){0.f, 0.f, 0.f, 0.f};
      Sv = __builtin_amdgcn_mfma_f32_16x16x32_f16(Kf0, Qf0, Sv, 0, 0, 0);
      Sv = __builtin_amdgcn_mfma_f32_16x16x32_f16(Kf1, Qf1, Sv, 0, 0, 0);

      f32x4 snv = ((const f32x4*)sNl)[t * 16 + 4 * ct + qd];   // broadcast
      f32x4 ev = Sv + snv + ss;                     // e * log2e
      f32x4 tv = __builtin_elementwise_max(ev, ev * 0.2f);  // leakyrelu
      unsigned bits = (unsigned)(m64 >> (16 * ct + 4 * qd));
      float p0 = __builtin_amdgcn_exp2f(tv.x);
      float p1 = __builtin_amdgcn_exp2f(tv.y);
      float p2 = __builtin_amdgcn_exp2f(tv.z);
      float p3 = __builtin_amdgcn_exp2f(tv.w);
      p0 = (bits & 1u) ? p0 : 0.f;
      p1 = (bits & 2u) ? p1 : 0.f;
      p2 = (bits & 4u) ? p2 : 0.f;
      p3 = (bits & 8u) ? p3 : 0.f;
      lsum += (p0 + p1) + (p2 + p3);
      fp16x2 plo = __builtin_amdgcn_cvt_pkrtz(p0, p1);
      fp16x2 phi = __builtin_amdgcn_cvt_pkrtz(p2, p3);
      h16x4 Pf = (h16x4){(_Float16)plo.x, (_Float16)plo.y,
                         (_Float16)phi.x, (_Float16)phi.y};  // P^T[j][i=c]

      // O^T[f][i] += V^T[f][j] * P^T[j][i]
#pragma unroll
      for (int ft = 0; ft < 4; ++ft) {
        h16x4 Vf = *(const h16x4*)&Tc[(16 * ft + c) * 64 +
                                      (((4 * ct + qd) ^ c) << 2)];
        O[ft] = __builtin_amdgcn_mfma_f32_16x16x16f16(Vf, Pf, O[ft], 0, 0, 0);
      }
    }

    if (t < 15) {                                   // fill the other buffer
      _Float16* K2 = &Kb[(t & 1) ^ 1][0];
      _Float16* T2 = &Tb[(t & 1) ^ 1][0];
      *(uint4*)&K2[srow * 64 + ksw] = kr0;
      *(uint4*)&K2[(srow + 32) * 64 + ksw] = kr1;
      uint4 s0 = tswap ? (uint4){tr0.z, tr0.w, tr0.x, tr0.y} : tr0;
      uint4 s1 = tswap ? (uint4){tr1.z, tr1.w, tr1.x, tr1.y} : tr1;
      *(uint4*)&T2[srow * 64 + tsw] = s0;
      *(uint4*)&T2[(srow + 32) * 64 + tsw] = s1;
    }
    m64 = mn;
  }

  // l: sum over qd groups (full j-quarter per row i=i0+c)
  lsum += __shfl_xor(lsum, 16, 64);
  lsum += __shfl_xor(lsum, 32, 64);

  float* orow = Opart + ((size_t)split * 16384 + bN + i0 + c) * 64;
#pragma unroll
  for (int ft = 0; ft < 4; ++ft)
    *(f32x4*)(orow + 16 * ft + 4 * qd) = O[ft];
  if (lane < 16) lpart[split * 16384 + bN + i0 + c] = lsum;
}

// ---------------- phase 3: combine splits + normalize + ELU ----------------
__global__ __launch_bounds__(256) void gat_combine(
    const float* __restrict__ Opart, const float* __restrict__ lpart,
    float* __restrict__ out)
{
  const int tid = threadIdx.x;
  const size_t row = (size_t)blockIdx.x * 16 + (tid >> 4);
  const int f4 = (tid & 15) * 4;
  const size_t R = 16384;
  float l = lpart[row] + lpart[R + row] + lpart[2 * R + row] + lpart[3 * R + row];
  f32x4 o = *(const f32x4*)&Opart[row * 64 + f4];
  o += *(const f32x4*)&Opart[(R + row) * 64 + f4];
  o += *(const f32x4*)&Opart[(2 * R + row) * 64 + f4];
  o += *(const f32x4*)&Opart[(3 * R + row) * 64 + f4];
  float inv = 1.0f / l;
  float4 res;
  float v;
  v = o.x * inv; res.x = v > 0.f ? v : __expf(v) - 1.f;
  v = o.y * inv; res.y = v > 0.f ? v : __expf(v) - 1.f;
  v = o.z * inv; res.z = v > 0.f ? v : __expf(v) - 1.f;
  v = o.w * inv; res.w = v > 0.f ? v : __expf(v) - 1.f;
  *(float4*)&out[row * 64 + f4] = res;
}

extern "C" void kernel_launch(void* const* d_in, const int* in_sizes, int n_in,
                              void* d_out, int out_size, void* d_ws, size_t ws_size,
                              hipStream_t stream) {
  const float* x  = (const float*)d_in[0];
  const int* adj  = (const int*)d_in[1];
  const float* W  = (const float*)d_in[2];
  const float* a  = (const float*)d_in[3];
  float* out = (float*)d_out;

  char* ws = (char*)d_ws;
  _Float16* h16  = (_Float16*)(ws);                      // 2 MB
  _Float16* hT16 = (_Float16*)(ws + (2u << 20));         // 2 MB
  _Float16* q16  = (_Float16*)(ws + (4u << 20));         // 2 MB
  float* sS = (float*)(ws + (6u << 20));                 // 64 KB
  float* sN = (float*)(ws + (6u << 20) + (64u << 10));   // 64 KB
  float* Opart = (float*)(ws + (6u << 20) + (128u << 10));               // 16.8 MB
  float* lpart = (float*)(ws + (6u << 20) + (128u << 10) + (17u << 20)); // 256 KB
  unsigned long long* mask =
      (unsigned long long*)(ws + (6u << 20) + (128u << 10) + (18u << 20)); // 8.4 MB

  gat_mask<<<4096, 256, 0, stream>>>(adj, mask);
  gat_phase1<<<512, 256, 0, stream>>>(x, W, a, h16, hT16, q16, sS, sN);
  gat_phase2<<<1024, 256, 0, stream>>>(h16, hT16, q16, sS, sN, mask, Opart, lpart);
  gat_combine<<<1024, 256, 0, stream>>>(Opart, lpart, out);
}

// Round 10
// 431.543 us; speedup vs baseline: 1.0820x; 1.0196x over previous
//
#include <hip/hip_runtime.h>

// GAT as flash-attention, round 10 = R9 with a copy-shaped mask kernel.
//  - R8 measured scattered-row adj reads at 1.9 TB/s; R9's gat_mask (one wave
//    per row, 256 B/inst, co-resident streams 16 KB apart) likely also ~2.3.
//    New gat_mask: one BLOCK per row, int4/lane (1 KB/inst), block walks its
//    16 KB row contiguously, consecutive blocks = consecutive rows ->
//    fill-kernel-shaped traffic (~6.5 TB/s).
//  - mask bit layout: word[row][k*4+c] bit l = adj[row][k*256+4l+c] > 0.
//    phase2 extracts per-tile 16-bit slices (unrolled tt -> constant shifts).
//  - phase2 otherwise identical to R9: double-buffered XOR-swizzled LDS
//    (0 conflicts), one __syncthreads/tile, fixed-scale softmax, S^T MFMA,
//    4-way j-split, 1024 blocks.

typedef __attribute__((ext_vector_type(4))) float f32x4;
typedef __attribute__((ext_vector_type(4))) _Float16 h16x4;
typedef __attribute__((ext_vector_type(8))) _Float16 h16x8;
typedef __attribute__((ext_vector_type(2))) __fp16 fp16x2;
typedef unsigned long long u64;

#define L2E 1.4426950408889634f

// ---------------- phase 0: adj -> bitmask (copy-shaped HBM stream) ----------
// 16384 blocks (one per row) x 256 thr. Wave w, pass p: chunk k=w+4p of 256
// ints; int4 per lane = 1 KB/inst; block covers its 16 KB row contiguously.
__global__ __launch_bounds__(256) void gat_mask(
    const int* __restrict__ adj,                 // [16384][4096]
    u64* __restrict__ mask)                      // [16384][64]
{
  const int tid = threadIdx.x;
  const int w = tid >> 6, lane = tid & 63;
  const size_t row = blockIdx.x;
  const int* ap = adj + row * 4096;
  u64* mp = mask + row * 64;
#pragma unroll
  for (int p = 0; p < 4; ++p) {
    const int k = w + 4 * p;                     // chunk of 256 j's
    int4 v = *(const int4*)(ap + k * 256 + 4 * lane);   // j = 256k+4*lane+c
    u64 b0 = __ballot(v.x > 0);
    u64 b1 = __ballot(v.y > 0);
    u64 b2 = __ballot(v.z > 0);
    u64 b3 = __ballot(v.w > 0);
    if (lane == 0) {
      mp[4 * k + 0] = b0;
      mp[4 * k + 1] = b1;
      mp[4 * k + 2] = b2;
      mp[4 * k + 3] = b3;
    }
  }
}

// ---------------- phase 1: h = x@W (fp32), scaled biases, fp16 packs --------
__global__ __launch_bounds__(256) void gat_phase1(
    const float* __restrict__ x,        // [4][4096][128]
    const float* __restrict__ W,        // [128][64]
    const float* __restrict__ a,        // [192]
    _Float16* __restrict__ h16,         // [4][4096][64]
    _Float16* __restrict__ hT16,        // [4][64][4096]
    _Float16* __restrict__ q16,         // [4][4096][64]  (pre-scaled by log2e)
    float* __restrict__ sS,             // [4][4096]      (pre-scaled by log2e)
    float* __restrict__ sN)             // [4][4096]      (pre-scaled by log2e)
{
  __shared__ float xs[32 * 132];        // x tile [row][k], stride 132
  __shared__ float ws[128 * 64];        // W natural [k][f] (broadcast/2-way)
  const int tid = threadIdx.x;
  const int bx  = blockIdx.x;
  const int b   = bx >> 7;
  const int n0  = (bx & 127) << 5;
  const float* xb = x + ((size_t)b * 4096 + n0) * 128;

#pragma unroll
  for (int p = 0; p < 4; ++p) {
    int idx = tid + p * 256;
    int row = idx >> 5, c4 = idx & 31;
    float4 v = ((const float4*)(xb + row * 128))[c4];
    *(float4*)&xs[row * 132 + c4 * 4] = v;
  }
#pragma unroll
  for (int p = 0; p < 8; ++p) {
    int idx = tid + p * 256;
    ((float4*)ws)[idx] = ((const float4*)W)[idx];
  }
  __syncthreads();

  const int tx = tid & 15;   // f = 4*tx + fi
  const int ty = tid >> 4;   // n = n0 + 2*ty + ri
  f32x4 acc0 = (f32x4){0.f, 0.f, 0.f, 0.f};
  f32x4 acc1 = (f32x4){0.f, 0.f, 0.f, 0.f};

#pragma unroll 8
  for (int k = 0; k < 128; k += 4) {
    f32x4 x0 = *(const f32x4*)&xs[(2 * ty) * 132 + k];
    f32x4 x1 = *(const f32x4*)&xs[(2 * ty + 1) * 132 + k];
    f32x4 w0 = *(const f32x4*)&ws[(k + 0) * 64 + 4 * tx];
    f32x4 w1 = *(const f32x4*)&ws[(k + 1) * 64 + 4 * tx];
    f32x4 w2 = *(const f32x4*)&ws[(k + 2) * 64 + 4 * tx];
    f32x4 w3 = *(const f32x4*)&ws[(k + 3) * 64 + 4 * tx];
    acc0 += x0.x * w0 + x0.y * w1 + x0.z * w2 + x0.w * w3;
    acc1 += x1.x * w0 + x1.y * w1 + x1.z * w2 + x1.w * w3;
  }
  float acc[2][4] = {{acc0.x, acc0.y, acc0.z, acc0.w},
                     {acc1.x, acc1.y, acc1.z, acc1.w}};

  float a1r[4], a2r[4], a3r[4];
#pragma unroll
  for (int f = 0; f < 4; ++f) {
    a1r[f] = a[4 * tx + f] * L2E;
    a2r[f] = a[64 + 4 * tx + f] * L2E;
    a3r[f] = a[128 + 4 * tx + f] * L2E;
  }
  const size_t bN = (size_t)b * 4096;
#pragma unroll
  for (int r = 0; r < 2; ++r) {
    float p1 = 0.f, p2 = 0.f;
#pragma unroll
    for (int f = 0; f < 4; ++f) { p1 += acc[r][f] * a1r[f]; p2 += acc[r][f] * a2r[f]; }
#pragma unroll
    for (int m = 1; m < 16; m <<= 1) {
      p1 += __shfl_xor(p1, m, 64);
      p2 += __shfl_xor(p2, m, 64);
    }
    if (tx == 0) {
      int n = n0 + 2 * ty + r;
      sS[bN + n] = p1;
      sN[bN + n] = p2;
    }
  }
#pragma unroll
  for (int r = 0; r < 2; ++r) {
    int n = n0 + 2 * ty + r;
    h16x4 hv, qv;
#pragma unroll
    for (int f = 0; f < 4; ++f) {
      hv[f] = (_Float16)acc[r][f];
      qv[f] = (_Float16)(acc[r][f] * a3r[f]);
    }
    *(h16x4*)&h16[(bN + n) * 64 + 4 * tx] = hv;
    *(h16x4*)&q16[(bN + n) * 64 + 4 * tx] = qv;
  }
  __syncthreads();                       // xs reads done; reuse as hT staging
  _Float16* hTs = (_Float16*)xs;         // [64][40] halves
#pragma unroll
  for (int f = 0; f < 4; ++f)
#pragma unroll
    for (int r = 0; r < 2; ++r)
      hTs[(4 * tx + f) * 40 + 2 * ty + r] = (_Float16)acc[r][f];
  __syncthreads();
  {
    int f = tid >> 2, part = tid & 3;
    uint4 v = *(uint4*)&hTs[f * 40 + 8 * part];
    *(uint4*)&hT16[((size_t)b * 64 + f) * 4096 + n0 + 8 * part] = v;
  }
}

// ---------------- phase 2: masked softmax-attention partials ----------------
// 1024 blocks (b(4), split(4), itile(64)) x 256 thr (4 waves x 16 rows).
// j-quarter = 1024 = 4 groups x 4 tiles of 64. Double-buffered XOR-swizzled
// LDS, one __syncthreads/tile. Mask: 4 words per 256-j group, bit
// (16*tt + 4*ct + qd) of word rr gates p_rr at j = ...+16ct+4qd+rr.
__global__ __launch_bounds__(256, 4) void gat_phase2(
    const _Float16* __restrict__ h16,
    const _Float16* __restrict__ hT16,
    const _Float16* __restrict__ q16,
    const float* __restrict__ sS,
    const float* __restrict__ sN,
    const u64* __restrict__ mask,       // [16384][64]
    float* __restrict__ Opart,          // [4][16384][64]
    float* __restrict__ lpart)          // [4][16384]
{
  __shared__ _Float16 Kb[2][4096];   // K tile [j][f], stride 64, chunk^(j&7)
  __shared__ _Float16 Tb[2][4096];   // V^T tile [f][j], stride 64, 8B-chunk^f
  __shared__ float sNl[1024];

  const int tid = threadIdx.x;
  const int w = tid >> 6, lane = tid & 63;
  const int qd = lane >> 4, c = lane & 15;
  const int bx = blockIdx.x;
  const int b = bx & 3;
  const int split = (bx >> 2) & 3;
  const int it = bx >> 4;
  const int i0 = it * 64 + w * 16;
  const int jq0 = split * 1024;
  const size_t bN = (size_t)b * 4096;

  // Q fragment (B-op of S^T): lane holds Q[i=i0+c][f-slice]
  const _Float16* qrow = q16 + (bN + i0 + c) * 64;
  h16x8 Qf0 = *(const h16x8*)(qrow + qd * 8);
  h16x8 Qf1 = *(const h16x8*)(qrow + 32 + qd * 8);
  const float ss = sS[bN + i0 + c];

  // mask words for this row; groups of 256 j = 4 words
  const u64* mrow = mask + (bN + i0 + c) * 64 + (jq0 >> 8) * 4;

  // staging addressing: thread -> rows srow, srow+32; 16B chunk (swizzled)
  const int srow = tid >> 3, chunk = tid & 7;
  const int ksw = (chunk ^ (srow & 7)) << 3;
  const int tsw = (chunk ^ ((srow >> 1) & 7)) << 3;
  const bool tswap = (srow & 1);
  const _Float16* hsrc = h16 + (bN + jq0 + srow) * 64 + chunk * 8;
  const _Float16* tsrc = hT16 + ((size_t)b * 64 + srow) * 4096 + jq0 + chunk * 8;

  f32x4 O[4];
#pragma unroll
  for (int ft = 0; ft < 4; ++ft) O[ft] = (f32x4){0.f, 0.f, 0.f, 0.f};
  float lsum = 0.f;

  // stage tile 0 into buffer 0, sN into LDS, mask group 0 into regs
  {
    uint4 k0 = *(const uint4*)hsrc, k1 = *(const uint4*)(hsrc + 32 * 64);
    uint4 t0 = *(const uint4*)tsrc, t1 = *(const uint4*)(tsrc + 32 * 4096);
    *(uint4*)&Kb[0][srow * 64 + ksw] = k0;
    *(uint4*)&Kb[0][(srow + 32) * 64 + ksw] = k1;
    uint4 s0 = tswap ? (uint4){t0.z, t0.w, t0.x, t0.y} : t0;
    uint4 s1 = tswap ? (uint4){t1.z, t1.w, t1.x, t1.y} : t1;
    *(uint4*)&Tb[0][srow * 64 + tsw] = s0;
    *(uint4*)&Tb[0][(srow + 32) * 64 + tsw] = s1;
  }
  ((f32x4*)sNl)[tid] = *(const f32x4*)(sN + bN + jq0 + 4 * tid);
  u64 W0 = mrow[0], W1 = mrow[1], W2 = mrow[2], W3 = mrow[3];

  for (int g = 0; g < 4; ++g) {
    u64 N0 = W0, N1 = W1, N2 = W2, N3 = W3;
    if (g < 3) {                                  // prefetch next mask group
      const u64* mg = mrow + 4 * (g + 1);
      N0 = mg[0]; N1 = mg[1]; N2 = mg[2]; N3 = mg[3];
    }
#pragma unroll
    for (int tt = 0; tt < 4; ++tt) {
      const int t = 4 * g + tt;
      __syncthreads();                            // buf[t&1] (+sNl) visible

      uint4 kr0, kr1, tr0, tr1;
      if (t < 15) {                               // staging prefetch (L2/L3)
        const _Float16* hs = hsrc + (t + 1) * 4096;
        const _Float16* ts = tsrc + (t + 1) * 64;
        kr0 = *(const uint4*)hs; kr1 = *(const uint4*)(hs + 32 * 64);
        tr0 = *(const uint4*)ts; tr1 = *(const uint4*)(ts + 32 * 4096);
      }

      // per-tile 16-bit slices (constant shift via unrolled tt), then >>qd
      const unsigned T0 = ((unsigned)(W0 >> (16 * tt))) >> qd;
      const unsigned T1 = ((unsigned)(W1 >> (16 * tt))) >> qd;
      const unsigned T2 = ((unsigned)(W2 >> (16 * tt))) >> qd;
      const unsigned T3 = ((unsigned)(W3 >> (16 * tt))) >> qd;

      const _Float16* Kc = &Kb[t & 1][0];
      const _Float16* Tc = &Tb[t & 1][0];
#pragma unroll
      for (int ct = 0; ct < 4; ++ct) {
        const int krow = 16 * ct + c;
        h16x8 Kf0 = *(const h16x8*)&Kc[krow * 64 + ((qd ^ (c & 7)) << 3)];
        h16x8 Kf1 = *(const h16x8*)&Kc[krow * 64 + (((qd + 4) ^ (c & 7)) << 3)];
        f32x4 Sv = (f32x4){0.f, 0.f, 0.f, 0.f};
        Sv = __builtin_amdgcn_mfma_f32_16x16x32_f16(Kf0, Qf0, Sv, 0, 0, 0);
        Sv = __builtin_amdgcn_mfma_f32_16x16x32_f16(Kf1, Qf1, Sv, 0, 0, 0);

        f32x4 snv = ((const f32x4*)sNl)[t * 16 + 4 * ct + qd];   // broadcast
        f32x4 ev = Sv + snv + ss;                 // e * log2e
        f32x4 tv = __builtin_elementwise_max(ev, ev * 0.2f);  // leakyrelu
        float p0 = __builtin_amdgcn_exp2f(tv.x);
        float p1 = __builtin_amdgcn_exp2f(tv.y);
        float p2 = __builtin_amdgcn_exp2f(tv.z);
        float p3 = __builtin_amdgcn_exp2f(tv.w);
        p0 = ((T0 >> (4 * ct)) & 1u) ? p0 : 0.f;
        p1 = ((T1 >> (4 * ct)) & 1u) ? p1 : 0.f;
        p2 = ((T2 >> (4 * ct)) & 1u) ? p2 : 0.f;
        p3 = ((T3 >> (4 * ct)) & 1u) ? p3 : 0.f;
        lsum += (p0 + p1) + (p2 + p3);
        fp16x2 plo = __builtin_amdgcn_cvt_pkrtz(p0, p1);
        fp16x2 phi = __builtin_amdgcn_cvt_pkrtz(p2, p3);
        h16x4 Pf = (h16x4){(_Float16)plo.x, (_Float16)plo.y,
                           (_Float16)phi.x, (_Float16)phi.y};  // P^T[j][i=c]

        // O^T[f][i] += V^T[f][j] * P^T[j][i]
#pragma unroll
        for (int ft = 0; ft < 4; ++ft) {
          h16x4 Vf = *(const h16x4*)&Tc[(16 * ft + c) * 64 +
                                        (((4 * ct + qd) ^ c) << 2)];
          O[ft] = __builtin_amdgcn_mfma_f32_16x16x16f16(Vf, Pf, O[ft], 0, 0, 0);
        }
      }

      if (t < 15) {                               // fill the other buffer
        _Float16* K2 = &Kb[(t & 1) ^ 1][0];
        _Float16* T2 = &Tb[(t & 1) ^ 1][0];
        *(uint4*)&K2[srow * 64 + ksw] = kr0;
        *(uint4*)&K2[(srow + 32) * 64 + ksw] = kr1;
        uint4 s0 = tswap ? (uint4){tr0.z, tr0.w, tr0.x, tr0.y} : tr0;
        uint4 s1 = tswap ? (uint4){tr1.z, tr1.w, tr1.x, tr1.y} : tr1;
        *(uint4*)&T2[srow * 64 + tsw] = s0;
        *(uint4*)&T2[(srow + 32) * 64 + tsw] = s1;
      }
    }
    W0 = N0; W1 = N1; W2 = N2; W3 = N3;
  }

  // l: sum over qd groups (full j-quarter per row i=i0+c)
  lsum += __shfl_xor(lsum, 16, 64);
  lsum += __shfl_xor(lsum, 32, 64);

  float* orow = Opart + ((size_t)split * 16384 + bN + i0 + c) * 64;
#pragma unroll
  for (int ft = 0; ft < 4; ++ft)
    *(f32x4*)(orow + 16 * ft + 4 * qd) = O[ft];
  if (lane < 16) lpart[split * 16384 + bN + i0 + c] = lsum;
}

// ---------------- phase 3: combine splits + normalize + ELU ----------------
__global__ __launch_bounds__(256) void gat_combine(
    const float* __restrict__ Opart, const float* __restrict__ lpart,
    float* __restrict__ out)
{
  const int tid = threadIdx.x;
  const size_t row = (size_t)blockIdx.x * 16 + (tid >> 4);
  const int f4 = (tid & 15) * 4;
  const size_t R = 16384;
  float l = lpart[row] + lpart[R + row] + lpart[2 * R + row] + lpart[3 * R + row];
  f32x4 o = *(const f32x4*)&Opart[row * 64 + f4];
  o += *(const f32x4*)&Opart[(R + row) * 64 + f4];
  o += *(const f32x4*)&Opart[(2 * R + row) * 64 + f4];
  o += *(const f32x4*)&Opart[(3 * R + row) * 64 + f4];
  float inv = 1.0f / l;
  float4 res;
  float v;
  v = o.x * inv; res.x = v > 0.f ? v : __expf(v) - 1.f;
  v = o.y * inv; res.y = v > 0.f ? v : __expf(v) - 1.f;
  v = o.z * inv; res.z = v > 0.f ? v : __expf(v) - 1.f;
  v = o.w * inv; res.w = v > 0.f ? v : __expf(v) - 1.f;
  *(float4*)&out[row * 64 + f4] = res;
}

extern "C" void kernel_launch(void* const* d_in, const int* in_sizes, int n_in,
                              void* d_out, int out_size, void* d_ws, size_t ws_size,
                              hipStream_t stream) {
  const float* x  = (const float*)d_in[0];
  const int* adj  = (const int*)d_in[1];
  const float* W  = (const float*)d_in[2];
  const float* a  = (const float*)d_in[3];
  float* out = (float*)d_out;

  char* ws = (char*)d_ws;
  _Float16* h16  = (_Float16*)(ws);                      // 2 MB
  _Float16* hT16 = (_Float16*)(ws + (2u << 20));         // 2 MB
  _Float16* q16  = (_Float16*)(ws + (4u << 20));         // 2 MB
  float* sS = (float*)(ws + (6u << 20));                 // 64 KB
  float* sN = (float*)(ws + (6u << 20) + (64u << 10));   // 64 KB
  float* Opart = (float*)(ws + (6u << 20) + (128u << 10));               // 16.8 MB
  float* lpart = (float*)(ws + (6u << 20) + (128u << 10) + (17u << 20)); // 256 KB
  u64* mask =
      (u64*)(ws + (6u << 20) + (128u << 10) + (18u << 20)); // 8.4 MB

  gat_mask<<<16384, 256, 0, stream>>>(adj, mask);
  gat_phase1<<<512, 256, 0, stream>>>(x, W, a, h16, hT16, q16, sS, sN);
  gat_phase2<<<1024, 256, 0, stream>>>(h16, hT16, q16, sS, sN, mask, Opart, lpart);
  gat_combine<<<1024, 256, 0, stream>>>(Opart, lpart, out);
}

// Round 11
// 418.931 us; speedup vs baseline: 1.1146x; 1.0301x over previous
//
#include <hip/hip_runtime.h>

// GAT as flash-attention, round 11 = R10 + phase2 anti-convoy fixes:
//  - __launch_bounds__(256,3): kill scratch spills (R8 measured WRITE_SIZE
//    103 MB = real spills under the (256,4) 128-VGPR cap).
//  - staging register double-buffer with 2-tile slack: tile t+2 loaded into
//    regs while tile t+1 (loaded 2 periods ago, landed) is written to LDS
//    right AFTER the barrier, BEFORE compute -> L3/cross-XCD staging latency
//    leaves the barrier-critical path.
//  - everything else = R10: copy-shaped mask kernel, XOR-swizzled LDS,
//    fixed-scale softmax, S^T MFMA, 4-way j-split, 1024 blocks.

typedef __attribute__((ext_vector_type(4))) float f32x4;
typedef __attribute__((ext_vector_type(4))) _Float16 h16x4;
typedef __attribute__((ext_vector_type(8))) _Float16 h16x8;
typedef __attribute__((ext_vector_type(2))) __fp16 fp16x2;
typedef unsigned long long u64;

#define L2E 1.4426950408889634f

// ---------------- phase 0: adj -> bitmask (copy-shaped HBM stream) ----------
// 16384 blocks (one per row) x 256 thr; int4/lane = 1 KB/inst contiguous.
// word[row][4k+c] bit l = adj[row][256k+4l+c] > 0.
__global__ __launch_bounds__(256) void gat_mask(
    const int* __restrict__ adj,                 // [16384][4096]
    u64* __restrict__ mask)                      // [16384][64]
{
  const int tid = threadIdx.x;
  const int w = tid >> 6, lane = tid & 63;
  const size_t row = blockIdx.x;
  const int* ap = adj + row * 4096;
  u64* mp = mask + row * 64;
#pragma unroll
  for (int p = 0; p < 4; ++p) {
    const int k = w + 4 * p;                     // chunk of 256 j's
    int4 v = *(const int4*)(ap + k * 256 + 4 * lane);   // j = 256k+4*lane+c
    u64 b0 = __ballot(v.x > 0);
    u64 b1 = __ballot(v.y > 0);
    u64 b2 = __ballot(v.z > 0);
    u64 b3 = __ballot(v.w > 0);
    if (lane == 0) {
      mp[4 * k + 0] = b0;
      mp[4 * k + 1] = b1;
      mp[4 * k + 2] = b2;
      mp[4 * k + 3] = b3;
    }
  }
}

// ---------------- phase 1: h = x@W (fp32), scaled biases, fp16 packs --------
__global__ __launch_bounds__(256) void gat_phase1(
    const float* __restrict__ x,        // [4][4096][128]
    const float* __restrict__ W,        // [128][64]
    const float* __restrict__ a,        // [192]
    _Float16* __restrict__ h16,         // [4][4096][64]
    _Float16* __restrict__ hT16,        // [4][64][4096]
    _Float16* __restrict__ q16,         // [4][4096][64]  (pre-scaled by log2e)
    float* __restrict__ sS,             // [4][4096]      (pre-scaled by log2e)
    float* __restrict__ sN)             // [4][4096]      (pre-scaled by log2e)
{
  __shared__ float xs[32 * 132];        // x tile [row][k], stride 132
  __shared__ float ws[128 * 64];        // W natural [k][f] (broadcast/2-way)
  const int tid = threadIdx.x;
  const int bx  = blockIdx.x;
  const int b   = bx >> 7;
  const int n0  = (bx & 127) << 5;
  const float* xb = x + ((size_t)b * 4096 + n0) * 128;

#pragma unroll
  for (int p = 0; p < 4; ++p) {
    int idx = tid + p * 256;
    int row = idx >> 5, c4 = idx & 31;
    float4 v = ((const float4*)(xb + row * 128))[c4];
    *(float4*)&xs[row * 132 + c4 * 4] = v;
  }
#pragma unroll
  for (int p = 0; p < 8; ++p) {
    int idx = tid + p * 256;
    ((float4*)ws)[idx] = ((const float4*)W)[idx];
  }
  __syncthreads();

  const int tx = tid & 15;   // f = 4*tx + fi
  const int ty = tid >> 4;   // n = n0 + 2*ty + ri
  f32x4 acc0 = (f32x4){0.f, 0.f, 0.f, 0.f};
  f32x4 acc1 = (f32x4){0.f, 0.f, 0.f, 0.f};

#pragma unroll 8
  for (int k = 0; k < 128; k += 4) {
    f32x4 x0 = *(const f32x4*)&xs[(2 * ty) * 132 + k];
    f32x4 x1 = *(const f32x4*)&xs[(2 * ty + 1) * 132 + k];
    f32x4 w0 = *(const f32x4*)&ws[(k + 0) * 64 + 4 * tx];
    f32x4 w1 = *(const f32x4*)&ws[(k + 1) * 64 + 4 * tx];
    f32x4 w2 = *(const f32x4*)&ws[(k + 2) * 64 + 4 * tx];
    f32x4 w3 = *(const f32x4*)&ws[(k + 3) * 64 + 4 * tx];
    acc0 += x0.x * w0 + x0.y * w1 + x0.z * w2 + x0.w * w3;
    acc1 += x1.x * w0 + x1.y * w1 + x1.z * w2 + x1.w * w3;
  }
  float acc[2][4] = {{acc0.x, acc0.y, acc0.z, acc0.w},
                     {acc1.x, acc1.y, acc1.z, acc1.w}};

  float a1r[4], a2r[4], a3r[4];
#pragma unroll
  for (int f = 0; f < 4; ++f) {
    a1r[f] = a[4 * tx + f] * L2E;
    a2r[f] = a[64 + 4 * tx + f] * L2E;
    a3r[f] = a[128 + 4 * tx + f] * L2E;
  }
  const size_t bN = (size_t)b * 4096;
#pragma unroll
  for (int r = 0; r < 2; ++r) {
    float p1 = 0.f, p2 = 0.f;
#pragma unroll
    for (int f = 0; f < 4; ++f) { p1 += acc[r][f] * a1r[f]; p2 += acc[r][f] * a2r[f]; }
#pragma unroll
    for (int m = 1; m < 16; m <<= 1) {
      p1 += __shfl_xor(p1, m, 64);
      p2 += __shfl_xor(p2, m, 64);
    }
    if (tx == 0) {
      int n = n0 + 2 * ty + r;
      sS[bN + n] = p1;
      sN[bN + n] = p2;
    }
  }
#pragma unroll
  for (int r = 0; r < 2; ++r) {
    int n = n0 + 2 * ty + r;
    h16x4 hv, qv;
#pragma unroll
    for (int f = 0; f < 4; ++f) {
      hv[f] = (_Float16)acc[r][f];
      qv[f] = (_Float16)(acc[r][f] * a3r[f]);
    }
    *(h16x4*)&h16[(bN + n) * 64 + 4 * tx] = hv;
    *(h16x4*)&q16[(bN + n) * 64 + 4 * tx] = qv;
  }
  __syncthreads();                       // xs reads done; reuse as hT staging
  _Float16* hTs = (_Float16*)xs;         // [64][40] halves
#pragma unroll
  for (int f = 0; f < 4; ++f)
#pragma unroll
    for (int r = 0; r < 2; ++r)
      hTs[(4 * tx + f) * 40 + 2 * ty + r] = (_Float16)acc[r][f];
  __syncthreads();
  {
    int f = tid >> 2, part = tid & 3;
    uint4 v = *(uint4*)&hTs[f * 40 + 8 * part];
    *(uint4*)&hT16[((size_t)b * 64 + f) * 4096 + n0 + 8 * part] = v;
  }
}

// ---------------- phase 2: masked softmax-attention partials ----------------
// 1024 blocks (b(4), split(4), itile(64)) x 256 thr (4 waves x 16 rows).
// j-quarter = 1024 = 4 groups x 4 tiles of 64. Double-buffered XOR-swizzled
// LDS; staging regs hold tiles t+1 and t+2 (2-period latency slack); write of
// t+1 happens right after the barrier, before compute.
__global__ __launch_bounds__(256, 3) void gat_phase2(
    const _Float16* __restrict__ h16,
    const _Float16* __restrict__ hT16,
    const _Float16* __restrict__ q16,
    const float* __restrict__ sS,
    const float* __restrict__ sN,
    const u64* __restrict__ mask,       // [16384][64]
    float* __restrict__ Opart,          // [4][16384][64]
    float* __restrict__ lpart)          // [4][16384]
{
  __shared__ _Float16 Kb[2][4096];   // K tile [j][f], stride 64, chunk^(j&7)
  __shared__ _Float16 Tb[2][4096];   // V^T tile [f][j], stride 64, 8B-chunk^f
  __shared__ float sNl[1024];

  const int tid = threadIdx.x;
  const int w = tid >> 6, lane = tid & 63;
  const int qd = lane >> 4, c = lane & 15;
  const int bx = blockIdx.x;
  const int b = bx & 3;
  const int split = (bx >> 2) & 3;
  const int it = bx >> 4;
  const int i0 = it * 64 + w * 16;
  const int jq0 = split * 1024;
  const size_t bN = (size_t)b * 4096;

  // Q fragment (B-op of S^T): lane holds Q[i=i0+c][f-slice]
  const _Float16* qrow = q16 + (bN + i0 + c) * 64;
  h16x8 Qf0 = *(const h16x8*)(qrow + qd * 8);
  h16x8 Qf1 = *(const h16x8*)(qrow + 32 + qd * 8);
  const float ss = sS[bN + i0 + c];

  // mask words for this row; groups of 256 j = 4 words
  const u64* mrow = mask + (bN + i0 + c) * 64 + (jq0 >> 8) * 4;

  // staging addressing: thread -> rows srow, srow+32; 16B chunk (swizzled)
  const int srow = tid >> 3, chunk = tid & 7;
  const int ksw = (chunk ^ (srow & 7)) << 3;
  const int tsw = (chunk ^ ((srow >> 1) & 7)) << 3;
  const bool tswap = (srow & 1);
  const _Float16* hsrc = h16 + (bN + jq0 + srow) * 64 + chunk * 8;
  const _Float16* tsrc = hT16 + ((size_t)b * 64 + srow) * 4096 + jq0 + chunk * 8;

  f32x4 O[4];
#pragma unroll
  for (int ft = 0; ft < 4; ++ft) O[ft] = (f32x4){0.f, 0.f, 0.f, 0.f};
  float lsum = 0.f;

  // stage tile 0 straight into buffer 0; hold tile 1 in regs (R1)
  {
    uint4 k0 = *(const uint4*)hsrc, k1 = *(const uint4*)(hsrc + 32 * 64);
    uint4 t0 = *(const uint4*)tsrc, t1 = *(const uint4*)(tsrc + 32 * 4096);
    *(uint4*)&Kb[0][srow * 64 + ksw] = k0;
    *(uint4*)&Kb[0][(srow + 32) * 64 + ksw] = k1;
    uint4 s0 = tswap ? (uint4){t0.z, t0.w, t0.x, t0.y} : t0;
    uint4 s1 = tswap ? (uint4){t1.z, t1.w, t1.x, t1.y} : t1;
    *(uint4*)&Tb[0][srow * 64 + tsw] = s0;
    *(uint4*)&Tb[0][(srow + 32) * 64 + tsw] = s1;
  }
  uint4 kr0 = *(const uint4*)(hsrc + 4096);
  uint4 kr1 = *(const uint4*)(hsrc + 4096 + 32 * 64);
  uint4 tr0 = *(const uint4*)(tsrc + 64);
  uint4 tr1 = *(const uint4*)(tsrc + 64 + 32 * 4096);

  ((f32x4*)sNl)[tid] = *(const f32x4*)(sN + bN + jq0 + 4 * tid);
  u64 W0 = mrow[0], W1 = mrow[1], W2 = mrow[2], W3 = mrow[3];

  for (int g = 0; g < 4; ++g) {
    u64 N0 = W0, N1 = W1, N2 = W2, N3 = W3;
    if (g < 3) {                                  // prefetch next mask group
      const u64* mg = mrow + 4 * (g + 1);
      N0 = mg[0]; N1 = mg[1]; N2 = mg[2]; N3 = mg[3];
    }
#pragma unroll
    for (int tt = 0; tt < 4; ++tt) {
      const int t = 4 * g + tt;
      __syncthreads();                            // buf[t&1] (+sNl) visible

      uint4 nk0, nk1, nt0, nt1;                   // R2 = tile t+2
      if (t < 14) {
        const _Float16* hs = hsrc + (t + 2) * 4096;
        const _Float16* ts = tsrc + (t + 2) * 64;
        nk0 = *(const uint4*)hs; nk1 = *(const uint4*)(hs + 32 * 64);
        nt0 = *(const uint4*)ts; nt1 = *(const uint4*)(ts + 32 * 4096);
      }
      if (t < 15) {                               // write tile t+1 (R1, landed)
        _Float16* K2 = &Kb[(t + 1) & 1][0];
        _Float16* T2 = &Tb[(t + 1) & 1][0];
        *(uint4*)&K2[srow * 64 + ksw] = kr0;
        *(uint4*)&K2[(srow + 32) * 64 + ksw] = kr1;
        uint4 s0 = tswap ? (uint4){tr0.z, tr0.w, tr0.x, tr0.y} : tr0;
        uint4 s1 = tswap ? (uint4){tr1.z, tr1.w, tr1.x, tr1.y} : tr1;
        *(uint4*)&T2[srow * 64 + tsw] = s0;
        *(uint4*)&T2[(srow + 32) * 64 + tsw] = s1;
      }

      // per-tile 16-bit slices (constant shift via unrolled tt), then >>qd
      const unsigned T0 = ((unsigned)(W0 >> (16 * tt))) >> qd;
      const unsigned T1 = ((unsigned)(W1 >> (16 * tt))) >> qd;
      const unsigned T2s = ((unsigned)(W2 >> (16 * tt))) >> qd;
      const unsigned T3 = ((unsigned)(W3 >> (16 * tt))) >> qd;

      const _Float16* Kc = &Kb[t & 1][0];
      const _Float16* Tc = &Tb[t & 1][0];
#pragma unroll
      for (int ct = 0; ct < 4; ++ct) {
        const int krow = 16 * ct + c;
        h16x8 Kf0 = *(const h16x8*)&Kc[krow * 64 + ((qd ^ (c & 7)) << 3)];
        h16x8 Kf1 = *(const h16x8*)&Kc[krow * 64 + (((qd + 4) ^ (c & 7)) << 3)];
        f32x4 Sv = (f32x4){0.f, 0.f, 0.f, 0.f};
        Sv = __builtin_amdgcn_mfma_f32_16x16x32_f16(Kf0, Qf0, Sv, 0, 0, 0);
        Sv = __builtin_amdgcn_mfma_f32_16x16x32_f16(Kf1, Qf1, Sv, 0, 0, 0);

        f32x4 snv = ((const f32x4*)sNl)[t * 16 + 4 * ct + qd];   // broadcast
        f32x4 ev = Sv + snv + ss;                 // e * log2e
        f32x4 tv = __builtin_elementwise_max(ev, ev * 0.2f);  // leakyrelu
        float p0 = __builtin_amdgcn_exp2f(tv.x);
        float p1 = __builtin_amdgcn_exp2f(tv.y);
        float p2 = __builtin_amdgcn_exp2f(tv.z);
        float p3 = __builtin_amdgcn_exp2f(tv.w);
        p0 = ((T0 >> (4 * ct)) & 1u) ? p0 : 0.f;
        p1 = ((T1 >> (4 * ct)) & 1u) ? p1 : 0.f;
        p2 = ((T2s >> (4 * ct)) & 1u) ? p2 : 0.f;
        p3 = ((T3 >> (4 * ct)) & 1u) ? p3 : 0.f;
        lsum += (p0 + p1) + (p2 + p3);
        fp16x2 plo = __builtin_amdgcn_cvt_pkrtz(p0, p1);
        fp16x2 phi = __builtin_amdgcn_cvt_pkrtz(p2, p3);
        h16x4 Pf = (h16x4){(_Float16)plo.x, (_Float16)plo.y,
                           (_Float16)phi.x, (_Float16)phi.y};  // P^T[j][i=c]

        // O^T[f][i] += V^T[f][j] * P^T[j][i]
#pragma unroll
        for (int ft = 0; ft < 4; ++ft) {
          h16x4 Vf = *(const h16x4*)&Tc[(16 * ft + c) * 64 +
                                        (((4 * ct + qd) ^ c) << 2)];
          O[ft] = __builtin_amdgcn_mfma_f32_16x16x16f16(Vf, Pf, O[ft], 0, 0, 0);
        }
      }

      kr0 = nk0; kr1 = nk1; tr0 = nt0; tr1 = nt1;   // rotate R2 -> R1
    }
    W0 = N0; W1 = N1; W2 = N2; W3 = N3;
  }

  // l: sum over qd groups (full j-quarter per row i=i0+c)
  lsum += __shfl_xor(lsum, 16, 64);
  lsum += __shfl_xor(lsum, 32, 64);

  float* orow = Opart + ((size_t)split * 16384 + bN + i0 + c) * 64;
#pragma unroll
  for (int ft = 0; ft < 4; ++ft)
    *(f32x4*)(orow + 16 * ft + 4 * qd) = O[ft];
  if (lane < 16) lpart[split * 16384 + bN + i0 + c] = lsum;
}

// ---------------- phase 3: combine splits + normalize + ELU ----------------
__global__ __launch_bounds__(256) void gat_combine(
    const float* __restrict__ Opart, const float* __restrict__ lpart,
    float* __restrict__ out)
{
  const int tid = threadIdx.x;
  const size_t row = (size_t)blockIdx.x * 16 + (tid >> 4);
  const int f4 = (tid & 15) * 4;
  const size_t R = 16384;
  float l = lpart[row] + lpart[R + row] + lpart[2 * R + row] + lpart[3 * R + row];
  f32x4 o = *(const f32x4*)&Opart[row * 64 + f4];
  o += *(const f32x4*)&Opart[(R + row) * 64 + f4];
  o += *(const f32x4*)&Opart[(2 * R + row) * 64 + f4];
  o += *(const f32x4*)&Opart[(3 * R + row) * 64 + f4];
  float inv = 1.0f / l;
  float4 res;
  float v;
  v = o.x * inv; res.x = v > 0.f ? v : __expf(v) - 1.f;
  v = o.y * inv; res.y = v > 0.f ? v : __expf(v) - 1.f;
  v = o.z * inv; res.z = v > 0.f ? v : __expf(v) - 1.f;
  v = o.w * inv; res.w = v > 0.f ? v : __expf(v) - 1.f;
  *(float4*)&out[row * 64 + f4] = res;
}

extern "C" void kernel_launch(void* const* d_in, const int* in_sizes, int n_in,
                              void* d_out, int out_size, void* d_ws, size_t ws_size,
                              hipStream_t stream) {
  const float* x  = (const float*)d_in[0];
  const int* adj  = (const int*)d_in[1];
  const float* W  = (const float*)d_in[2];
  const float* a  = (const float*)d_in[3];
  float* out = (float*)d_out;

  char* ws = (char*)d_ws;
  _Float16* h16  = (_Float16*)(ws);                      // 2 MB
  _Float16* hT16 = (_Float16*)(ws + (2u << 20));         // 2 MB
  _Float16* q16  = (_Float16*)(ws + (4u << 20));         // 2 MB
  float* sS = (float*)(ws + (6u << 20));                 // 64 KB
  float* sN = (float*)(ws + (6u << 20) + (64u << 10));   // 64 KB
  float* Opart = (float*)(ws + (6u << 20) + (128u << 10));               // 16.8 MB
  float* lpart = (float*)(ws + (6u << 20) + (128u << 10) + (17u << 20)); // 256 KB
  u64* mask =
      (u64*)(ws + (6u << 20) + (128u << 10) + (18u << 20)); // 8.4 MB

  gat_mask<<<16384, 256, 0, stream>>>(adj, mask);
  gat_phase1<<<512, 256, 0, stream>>>(x, W, a, h16, hT16, q16, sS, sN);
  gat_phase2<<<1024, 256, 0, stream>>>(h16, hT16, q16, sS, sN, mask, Opart, lpart);
  gat_combine<<<1024, 256, 0, stream>>>(Opart, lpart, out);
}